// Round 1
// baseline (195.459 us; speedup 1.0000x reference)
//
#include <hip/hip_runtime.h>

// Problem: B=8, T=4096, H=1024, all fp32.
// score[b,t] = states[b,t,:] · (W[0] @ ctx[b,:]) + bias
// Split: K1 computes v[b,i] (8192 floats, in d_ws); K2 does the big
// memory-bound pass over states (128 MiB) — HBM roofline ~22 us.

#define HDIM 1024
#define BDIM 8
#define TDIM 4096

// ---------- Kernel 1: v[b,i] = sum_j W[i*H+j] * ctx[b*H+j] ----------
// One wave per (b,i). 8192 waves -> 2048 blocks x 256 threads.
__global__ __launch_bounds__(256) void gs_compute_v(
    const float* __restrict__ W,
    const float* __restrict__ ctx,
    float* __restrict__ v)
{
    const int wave = (blockIdx.x << 2) | (threadIdx.x >> 6);   // [0, 8192)
    const int lane = threadIdx.x & 63;
    const int b = wave >> 10;          // [0,8)
    const int i = wave & (HDIM - 1);   // [0,1024)

    const float4* __restrict__ Wrow = (const float4*)(W + (size_t)i * HDIM);
    const float4* __restrict__ Crow = (const float4*)(ctx + (size_t)b * HDIM);

    float acc = 0.0f;
#pragma unroll
    for (int k = 0; k < 4; ++k) {       // 4 * 64 lanes * 4 floats = 1024
        float4 w4 = Wrow[k * 64 + lane];
        float4 c4 = Crow[k * 64 + lane];
        acc += w4.x * c4.x + w4.y * c4.y + w4.z * c4.z + w4.w * c4.w;
    }
#pragma unroll
    for (int off = 32; off > 0; off >>= 1)
        acc += __shfl_down(acc, off, 64);

    if (lane == 0) v[wave] = acc;
}

// ---------- Kernel 2: out[b,t] = states[b,t,:] . v[b,:] + bias ----------
// One wave per (b,t) row. 32768 waves -> 8192 blocks x 256 threads.
// Each wave reads one contiguous 4 KiB row via float4 (fully coalesced).
__global__ __launch_bounds__(256) void gs_compute_scores(
    const float* __restrict__ states,
    const float* __restrict__ v,
    const float* __restrict__ bias,
    float* __restrict__ out)
{
    const int row = (blockIdx.x << 2) | (threadIdx.x >> 6);    // [0, B*T)
    const int lane = threadIdx.x & 63;
    const int b = row >> 12;                                   // T = 4096

    const float4* __restrict__ Srow = (const float4*)(states + (size_t)row * HDIM);
    const float4* __restrict__ Vrow = (const float4*)(v + (size_t)b * HDIM);

    float acc = 0.0f;
#pragma unroll
    for (int k = 0; k < 4; ++k) {
        float4 s4 = Srow[k * 64 + lane];
        float4 v4 = Vrow[k * 64 + lane];
        acc += s4.x * v4.x + s4.y * v4.y + s4.z * v4.z + s4.w * v4.w;
    }
#pragma unroll
    for (int off = 32; off > 0; off >>= 1)
        acc += __shfl_down(acc, off, 64);

    if (lane == 0) out[row] = acc + bias[0];
}

extern "C" void kernel_launch(void* const* d_in, const int* in_sizes, int n_in,
                              void* d_out, int out_size, void* d_ws, size_t ws_size,
                              hipStream_t stream)
{
    const float* states = (const float*)d_in[0];  // (B, T, H)
    const float* ctx    = (const float*)d_in[1];  // (B, H)
    const float* W      = (const float*)d_in[2];  // (1, H, H)
    const float* bias   = (const float*)d_in[3];  // (1,)
    float* out = (float*)d_out;                   // (B, T, 1) fp32
    float* v   = (float*)d_ws;                    // B*H floats = 32 KiB scratch

    gs_compute_v<<<dim3((BDIM * HDIM) / 4), dim3(256), 0, stream>>>(W, ctx, v);
    gs_compute_scores<<<dim3((BDIM * TDIM) / 4), dim3(256), 0, stream>>>(states, v, bias, out);
}

// Round 3
// 184.868 us; speedup vs baseline: 1.0573x; 1.0573x over previous
//
#include <hip/hip_runtime.h>

// Problem: B=8, T=4096, H=1024, all fp32.
// score[b,t] = states[b,t,:] · (W[0] @ ctx[b,:]) + bias
// K1 computes v[b,i] (8192 floats, in d_ws); K2 does the big memory-bound
// pass over states (128 MiB) — HBM roofline ~21 us for K2, ~1-2 us for K1.

#define HDIM 1024
#define BDIM 8
#define TDIM 4096

// native clang vector type — required by __builtin_nontemporal_load
typedef float v4f __attribute__((ext_vector_type(4)));

// ---------- Kernel 1: v[b,i] = sum_j W[i*H+j] * ctx[b*H+j] ----------
// One wave per (i,b), i-major: wave w -> i = w>>3, b = w&7, so the 8 waves
// sharing W row i are adjacent (same block pair) -> W row stays L1/L2-hot
// and W is fetched ~once (4 MiB) instead of up to 8x.
__global__ __launch_bounds__(256) void gs_compute_v(
    const float* __restrict__ W,
    const float* __restrict__ ctx,
    float* __restrict__ v)
{
    const int wave = (blockIdx.x << 2) | (threadIdx.x >> 6);   // [0, 8192)
    const int lane = threadIdx.x & 63;
    const int i = wave >> 3;           // [0,1024)  W row
    const int b = wave & 7;            // [0,8)

    const v4f* __restrict__ Wrow = (const v4f*)(W + (size_t)i * HDIM);
    const v4f* __restrict__ Crow = (const v4f*)(ctx + (size_t)b * HDIM);

    float acc = 0.0f;
#pragma unroll
    for (int k = 0; k < 4; ++k) {       // 4 * 64 lanes * 4 floats = 1024
        v4f w4 = Wrow[k * 64 + lane];
        v4f c4 = Crow[k * 64 + lane];
        acc += w4.x * c4.x + w4.y * c4.y + w4.z * c4.z + w4.w * c4.w;
    }
#pragma unroll
    for (int off = 32; off > 0; off >>= 1)
        acc += __shfl_down(acc, off, 64);

    if (lane == 0) v[b * HDIM + i] = acc;
}

// ---------- Kernel 2: out[b,t] = states[b,t,:] . v[b,:] + bias ----------
// One wave per (b,t) row; contiguous 4 KiB row via float4, fully coalesced.
// states is streamed (zero reuse) -> non-temporal loads so it doesn't evict
// the small L2-resident v.
__global__ __launch_bounds__(256) void gs_compute_scores(
    const float* __restrict__ states,
    const float* __restrict__ v,
    const float* __restrict__ bias,
    float* __restrict__ out)
{
    const int row = (blockIdx.x << 2) | (threadIdx.x >> 6);    // [0, B*T)
    const int lane = threadIdx.x & 63;
    const int b = row >> 12;                                   // T = 4096

    const v4f* __restrict__ Srow = (const v4f*)(states + (size_t)row * HDIM);
    const v4f* __restrict__ Vrow = (const v4f*)(v + (size_t)b * HDIM);

    float acc = 0.0f;
#pragma unroll
    for (int k = 0; k < 4; ++k) {
        v4f s4 = __builtin_nontemporal_load(&Srow[k * 64 + lane]);
        v4f v4 = Vrow[k * 64 + lane];
        acc += s4.x * v4.x + s4.y * v4.y + s4.z * v4.z + s4.w * v4.w;
    }
#pragma unroll
    for (int off = 32; off > 0; off >>= 1)
        acc += __shfl_down(acc, off, 64);

    if (lane == 0) out[row] = acc + bias[0];
}

extern "C" void kernel_launch(void* const* d_in, const int* in_sizes, int n_in,
                              void* d_out, int out_size, void* d_ws, size_t ws_size,
                              hipStream_t stream)
{
    const float* states = (const float*)d_in[0];  // (B, T, H)
    const float* ctx    = (const float*)d_in[1];  // (B, H)
    const float* W      = (const float*)d_in[2];  // (1, H, H)
    const float* bias   = (const float*)d_in[3];  // (1,)
    float* out = (float*)d_out;                   // (B, T, 1) fp32
    float* v   = (float*)d_ws;                    // B*H floats = 32 KiB scratch

    gs_compute_v<<<dim3((BDIM * HDIM) / 4), dim3(256), 0, stream>>>(W, ctx, v);
    gs_compute_scores<<<dim3((BDIM * TDIM) / 4), dim3(256), 0, stream>>>(states, v, bias, out);
}